// Round 9
// baseline (196.611 us; speedup 1.0000x reference)
//
#include <hip/hip_runtime.h>
#include <hip/hip_bf16.h>
#include <stdint.h>

constexpr int BH  = 16;    // batch*head
constexpr int LEN = 2048;
constexpr int DK  = 128;
constexpr int RND = 4;
constexpr int NB2 = 16;    // n_buckets/2 (chunk count)
constexpr int BL2 = 128;   // queries per chunk

typedef __attribute__((ext_vector_type(8)))  short short8;
typedef __attribute__((ext_vector_type(4)))  float f32x4;
typedef __attribute__((ext_vector_type(16))) float f32x16;

__device__ __forceinline__ float bflo(uint32_t u){ return __uint_as_float(u << 16); }
__device__ __forceinline__ float bfhi(uint32_t u){ return __uint_as_float(u & 0xffff0000u); }
__device__ __forceinline__ uint16_t f2b(float x){
  uint32_t u = __float_as_uint(x);
  return (uint16_t)((u + 0x7fffu + ((u >> 16) & 1u)) >> 16);   // RNE
}
__device__ __forceinline__ uint32_t pk2(float a, float b){
  return (uint32_t)f2b(a) | ((uint32_t)f2b(b) << 16);
}

// ---------------- kernel 1: 64 tokens/block; register-tiled fp32 GEMM hash ----------------
// rm_s [d][col] (native layout), qT [d][tok]. Thread (tt,cc) computes 4 tok x 4 col.
// Round r == wave index; argmax combined across col-subgroups via shfl_xor(16/32).
__global__ __launch_bounds__(256) void k_hash(const float* __restrict__ q,
    const float* __restrict__ v, const float* __restrict__ rm,
    uint16_t* __restrict__ fqb, uint16_t* __restrict__ vbb,
    uint8_t* __restrict__ hsh)
{
  __shared__ float rm_s[128*64];    // 32 KB
  __shared__ float qT[128*64];      // 32 KB
  __shared__ float invn_s[64];
  int b = blockIdx.x >> 5, chunk = blockIdx.x & 31;
  int t = threadIdx.x;
  // stage rm straight (it is [d][r][k] row-major = [d][64 cols])
  const float4* rm4 = (const float4*)(rm + (size_t)b*8192);
  #pragma unroll
  for (int i=0;i<8;i++) ((float4*)rm_s)[i*256 + t] = rm4[i*256 + t];
  // stage q (normalize) + bf16 conversions; token tl, d-slice qq*32..+31
  int tl = t >> 2, qq = t & 3;
  int tok = chunk*64 + tl;
  size_t ro = ((size_t)b*LEN + tok)*DK;
  float qs[32];
  float ss = 0.f;
  #pragma unroll
  for (int i=0;i<8;i++){
    float4 w = *(const float4*)(q + ro + qq*32 + i*4);
    qs[i*4]=w.x; qs[i*4+1]=w.y; qs[i*4+2]=w.z; qs[i*4+3]=w.w;
    ss += w.x*w.x + w.y*w.y + w.z*w.z + w.w*w.w;
  }
  ss += __shfl_xor(ss,1); ss += __shfl_xor(ss,2);
  float rn = 1.0f / sqrtf(ss);
  #pragma unroll
  for (int i=0;i<32;i++) qs[i] *= rn;
  #pragma unroll
  for (int i=0;i<4;i++){
    uint4 u;
    u.x = pk2(qs[i*8+0], qs[i*8+1]); u.y = pk2(qs[i*8+2], qs[i*8+3]);
    u.z = pk2(qs[i*8+4], qs[i*8+5]); u.w = pk2(qs[i*8+6], qs[i*8+7]);
    *(uint4*)(fqb + ro + qq*32 + i*8) = u;
  }
  #pragma unroll
  for (int i=0;i<4;i++){
    float4 a = *(const float4*)(v + ro + qq*32 + i*8);
    float4 c = *(const float4*)(v + ro + qq*32 + i*8 + 4);
    uint4 u;
    u.x = pk2(a.x,a.y); u.y = pk2(a.z,a.w); u.z = pk2(c.x,c.y); u.w = pk2(c.z,c.w);
    *(uint4*)(vbb + ro + qq*32 + i*8) = u;
  }
  #pragma unroll
  for (int i=0;i<32;i++) qT[(qq*32+i)*64 + tl] = qs[i];
  __syncthreads();
  if (t < 64){                      // rm column inverse norms (banks spread by t%32)
    float s2 = 0.f;
    for (int d=0; d<128; d++){ float w = rm_s[d*64+t]; s2 += w*w; }
    invn_s[t] = 1.0f / sqrtf(s2);
  }
  // GEMM: 4x4 register tile
  int tt = t & 15, cc = t >> 4;
  f32x4 a0={0,0,0,0}, a1={0,0,0,0}, a2={0,0,0,0}, a3={0,0,0,0};
  const float* qTp = qT   + tt*4;
  const float* rmp = rm_s + cc*4;
  #pragma unroll 8
  for (int d=0; d<128; d++){
    float4 qv = *(const float4*)(qTp + d*64);
    float4 rv = *(const float4*)(rmp + d*64);
    a0[0]+=qv.x*rv.x; a0[1]+=qv.x*rv.y; a0[2]+=qv.x*rv.z; a0[3]+=qv.x*rv.w;
    a1[0]+=qv.y*rv.x; a1[1]+=qv.y*rv.y; a1[2]+=qv.y*rv.z; a1[3]+=qv.y*rv.w;
    a2[0]+=qv.z*rv.x; a2[1]+=qv.z*rv.y; a2[2]+=qv.z*rv.z; a2[3]+=qv.z*rv.w;
    a3[0]+=qv.w*rv.x; a3[1]+=qv.w*rv.y; a3[2]+=qv.w*rv.z; a3[3]+=qv.w*rv.w;
  }
  __syncthreads();                  // invn_s ready
  float rin[4];
  #pragma unroll
  for (int j=0;j<4;j++) rin[j] = invn_s[cc*4+j];
  int r = cc >> 2;                  // round == wave
  int m = cc & 3;                   // col subgroup
  float bp[4], bn[4]; int bip[4], bin[4];
  #pragma unroll
  for (int i=0;i<4;i++){ bp[i]=-1e30f; bn[i]=-1e30f; bip[i]=0; bin[i]=16; }
  #pragma unroll
  for (int j=0;j<4;j++){
    int col = m*4 + j;              // k within round, 0..15
    #pragma unroll
    for (int i=0;i<4;i++){
      float hv = (i==0?a0[j]:i==1?a1[j]:i==2?a2[j]:a3[j]) * rin[j];
      if ( hv > bp[i]){ bp[i] =  hv; bip[i] = col; }
      if (-hv > bn[i]){ bn[i] = -hv; bin[i] = col + 16; }
    }
  }
  #pragma unroll
  for (int off=16; off<=32; off<<=1){
    #pragma unroll
    for (int i=0;i<4;i++){
      float op = __shfl_xor(bp[i], off); int oip = __shfl_xor(bip[i], off);
      if (op > bp[i] || (op == bp[i] && oip < bip[i])){ bp[i]=op; bip[i]=oip; }
      float on = __shfl_xor(bn[i], off); int oin = __shfl_xor(bin[i], off);
      if (on > bn[i] || (on == bn[i] && oin < bin[i])){ bn[i]=on; bin[i]=oin; }
    }
  }
  if (m == 0){                      // one writer per (round, token-group)
    uint32_t pk = 0;
    #pragma unroll
    for (int i=0;i<4;i++){
      int bidx = (bn[i] > bp[i]) ? bin[i] : bip[i];
      pk |= (uint32_t)bidx << (8*i);
    }
    *(uint32_t*)(hsh + ((size_t)(b*RND + r))*LEN + chunk*64 + tt*4) = pk;
  }
}

// ---------------- kernel 2: stable counting sort per (b,r), parallel scan ----------------
// hist padded to stride 257 so the k-major scan reads spread across banks
// (old stride 256: bank == e for all 64 lanes -> 64-way serialization).
__global__ __launch_bounds__(256) void k_sort(const uint8_t* __restrict__ hsh,
    int* __restrict__ posA, int* __restrict__ tokA)
{
  __shared__ int hist[32*257];
  __shared__ int wtot[4];
  int br = blockIdx.x;
  int t = threadIdx.x;
  const uint8_t* hh = hsh + (size_t)br*LEN;
  uint8_t ub[8];
  #pragma unroll
  for (int i=0;i<8;i++) ub[i] = hh[t*8+i];
  #pragma unroll
  for (int k=0;k<32;k++) hist[k*257+t] = 0;
  __syncthreads();
  #pragma unroll
  for (int i=0;i<8;i++) hist[(int)ub[i]*257 + t] += 1;
  __syncthreads();
  // thread t sums bucket k=t>>3, entries t' = (t&7)*32 + e  (k-major flattening)
  int base = (t>>3)*257 + (t&7)*32, s0 = 0;
  for (int e=0;e<32;e++) s0 += hist[base + ((e + t) & 31)];   // rotated: bank-spread
  int x = s0;
  #pragma unroll
  for (int off=1; off<64; off<<=1){
    int y = __shfl_up(x, off);
    if ((t & 63) >= off) x += y;
  }
  if ((t & 63) == 63) wtot[t>>6] = x;
  __syncthreads();
  int add = 0;
  #pragma unroll
  for (int i2=0;i2<4;i2++) add += (i2 < (t>>6)) ? wtot[i2] : 0;
  int run = x - s0 + add;
  for (int e=0;e<32;e++){ int tmp = hist[base+e]; hist[base+e] = run; run += tmp; }
  __syncthreads();
  #pragma unroll
  for (int i=0;i<8;i++){
    int l = t*8+i, k = ub[i];
    int p = hist[k*257+t]++;
    posA[(size_t)br*LEN + l] = p;
    tokA[(size_t)br*LEN + p] = l | (k << 11);
  }
}

// ---------------- kernel 3: fused MFMA attention, 32x32x16 ----------------
// Round 9 (on passing R8 body): (a) Ks chunk-XOR swizzle -- 16B chunk g of row kv
// stored at slot g^(kv&15), stride 136->128 u16. Kills the 4-way QK read conflict
// (lane stride 272B -> bank step 4 -> 4 lanes/bank); swizzled reads spread over
// all 16 slots -> 2 lanes/bank (free, m136). (b) LDS 40704->39680 => exactly
// 4 blocks/CU; __launch_bounds__(256,4) to allow it (double-buffer kept -- the
// (256,4)+single-buffer NaN was the single-buffer, proven R6). (c) s_setprio(1)
// around MFMA clusters (T5). Everything else identical to R8.
__global__ __launch_bounds__(256, 4) void k_fattn(
    const uint16_t* __restrict__ fqb, const uint16_t* __restrict__ vbb,
    const int* __restrict__ posA, const int* __restrict__ tokA,
    uint16_t* __restrict__ attb, float* __restrict__ rowsum)
{
  __shared__ __align__(16) char smem[39680];
  uint16_t* Ks0 = (uint16_t*)smem;               // 32*128*2 = 8192 (chunk-XOR swz)
  uint16_t* Ks1 = (uint16_t*)(smem + 8192);      // 8192
  uint16_t* VT0 = (uint16_t*)(smem + 16384);     // 128*40*2 = 10240 (swizzled V^T)
  uint16_t* VT1 = (uint16_t*)(smem + 26624);     // 10240
  uint32_t* km4 = (uint32_t*)(smem + 36864);     // 64 groups * 8 words = 2048
  uint16_t* tokS= (uint16_t*)(smem + 38912);     // 256*2 = 512
  uint16_t* qtokS=(uint16_t*)(smem + 39424);     // 128*2 = 256
  uint16_t* Qb  = (uint16_t*)smem;               // epilogue alias (17408 B; Ks+VT0-head dead)

  int bid0 = blockIdx.x;
  int bid = ((bid0 & 7) << 7) | (bid0 >> 3);     // XCD swizzle: each XCD gets 2 b's
  int n = bid & 15, r = (bid>>4)&3, b = bid>>6;
  int t = threadIdx.x;
  int w = t >> 6, lane = t & 63, l31 = lane & 31, h = lane >> 5;
  int br = b*RND + r;
  int sbase = br*LEN, qs0 = n*BL2;
  size_t gbase = (size_t)b*LEN;

  // key metadata (k_meta fused): group gi covers sorted keys 4gi..4gi+3
  // words: [km01, km23, ck01, ck23, cp01, cp23, -, -]
  if (t < 64){
    uint32_t km[4], ck[4], cp[4];
    #pragma unroll
    for (int j=0;j<4;j++){
      int sk4 = t*4 + j;
      int sk = (sk4 < BL2) ? (((n+NB2-1)&15)*BL2 + sk4) : (n*BL2 + sk4 - BL2);
      int raw = tokA[sbase + sk];
      int tok = raw & 2047;
      uint32_t code = 0;
      #pragma unroll
      for (int r2=0;r2<4;r2++){
        int p = posA[(size_t)(b*4+r2)*LEN + tok];
        code |= (uint32_t)(p >> 7) << (4*r2);
      }
      km[j] = (uint32_t)raw & 0xFFFFu;
      ck[j] = code;
      cp[j] = ((code & 0x7777u) + 0x1111u) ^ (code & 0x8888u);
      tokS[sk4] = (uint16_t)tok;
    }
    uint32_t* gp = km4 + t*8;
    gp[0] = km[0] | (km[1]<<16); gp[1] = km[2] | (km[3]<<16);
    gp[2] = ck[0] | (ck[1]<<16); gp[3] = ck[2] | (ck[3]<<16);
    gp[4] = cp[0] | (cp[1]<<16); gp[5] = cp[2] | (cp[3]<<16);
  }
  int raw_q = tokA[sbase + qs0 + w*32 + l31];
  int tokq = raw_q & 2047;
  uint32_t mq16 = (uint32_t)raw_q & 0xFFFFu;
  uint32_t cq = 0;
  #pragma unroll
  for (int r2=0;r2<4;r2++){
    int p = posA[(size_t)(b*4+r2)*LEN + tokq];
    cq |= (uint32_t)(p >> 7) << (4*r2);
  }
  uint32_t mq2 = mq16 | (mq16 << 16);
  uint32_t cq2 = cq | (cq << 16);
  qtokS[w*32 + l31] = (uint16_t)tokq;            // orig token of q-row (dup write by h)
  short8 qf[8];
  {
    const uint16_t* qrow = fqb + (gbase + tokq)*DK + h*8;
    #pragma unroll
    for (int dc=0;dc<8;dc++) qf[dc] = *(const short8*)(qrow + dc*16);
  }

  f32x16 O[4];
  #pragma unroll
  for (int i=0;i<4;i++)
    #pragma unroll
    for (int j=0;j<16;j++) O[i][j] = 0.f;
  float rsp = 0.f;

  int srow = t >> 3, sgp = t & 7;
  int ksw0 = ((2*sgp)     ^ (srow & 15))*8;      // Ks swizzled chunk slots
  int ksw1 = ((2*sgp + 1) ^ (srow & 15))*8;
  // V^T swizzled slot for this thread's kv=srow, d-group sgp (d>>4 == sgp)
  int swz_kv = (srow & 7) + 8*((srow >> 3) ^ (sgp & 3));
  __syncthreads();
  {
    int tok = (int)tokS[srow];
    const uint16_t* fr = fqb + (gbase + tok)*DK;
    const uint16_t* vr = vbb + (gbase + tok)*DK;
    uint16_t* kr = Ks0 + srow*128;
    *(uint4*)(kr + ksw0) = *(const uint4*)(fr + sgp*16);
    *(uint4*)(kr + ksw1) = *(const uint4*)(fr + sgp*16 + 8);
    uint4 v0 = *(const uint4*)(vr + sgp*16);
    uint4 v1 = *(const uint4*)(vr + sgp*16 + 8);
    uint16_t* vt = VT0 + (sgp*16)*40 + swz_kv;
    uint32_t vv[8] = {v0.x,v0.y,v0.z,v0.w,v1.x,v1.y,v1.z,v1.w};
    #pragma unroll
    for (int i2=0;i2<8;i2++){
      vt[(2*i2)*40]   = (uint16_t)(vv[i2] & 0xFFFFu);
      vt[(2*i2+1)*40] = (uint16_t)(vv[i2] >> 16);
    }
  }

  uint16_t* Kc = Ks0; uint16_t* Vc = VT0;
  uint16_t* Ka = Ks1; uint16_t* Va = VT1;

  for (int c=0;c<8;c++){
    __syncthreads();                 // slice-c buffers ready; prior reads done
    // ---- issue stage loads for slice c+1 (latency hides under this whole iter)
    uint4 kst0, kst1, vst0, vst1;
    if (c < 7){
      int tok = (int)tokS[(c+1)*32 + srow];
      const uint16_t* fr = fqb + (gbase + tok)*DK;
      const uint16_t* vr = vbb + (gbase + tok)*DK;
      kst0 = *(const uint4*)(fr + sgp*16);
      kst1 = *(const uint4*)(fr + sgp*16 + 8);
      vst0 = *(const uint4*)(vr + sgp*16);
      vst1 = *(const uint4*)(vr + sgp*16 + 8);
    }
    // ---- S^T = K * Q^T (swizzled Ks reads: 2 lanes/bank) ----
    f32x16 S;
    #pragma unroll
    for (int j=0;j<16;j++) S[j] = 0.f;
    __builtin_amdgcn_s_setprio(1);
    #pragma unroll
    for (int dc=0;dc<8;dc++){
      short8 a = *(const short8*)(Kc + l31*128 + (((dc<<1) + h) ^ (l31 & 15))*8);
      S = __builtin_amdgcn_mfma_f32_32x32x16_bf16(a, qf[dc], S, 0, 0, 0);
    }
    __builtin_amdgcn_s_setprio(0);
    // ---- epilogue: packed 2-keys-per-word mask/count math ----
    uint32_t u[8];
    #pragma unroll
    for (int g=0; g<4; g++){
      const uint32_t* gp = km4 + (c*8 + 2*g + h)*8;
      uint4 A  = *(const uint4*)gp;
      uint2 Bv = *(const uint2*)(gp + 4);
      #pragma unroll
      for (int p=0; p<2; p++){
        uint32_t kmp = p ? A.y : A.x;
        uint32_t ckp = p ? A.w : A.z;
        uint32_t cpp = p ? Bv.y : Bv.x;
        uint32_t xr2 = mq2 ^ kmp;
        uint32_t x1 = cq2 ^ ckp, x2 = cq2 ^ cpp;
        uint32_t h1 = ~(((x1 & 0x77777777u) + 0x77777777u) | x1) & 0x88888888u;
        uint32_t h2 = ~(((x2 & 0x77777777u) + 0x77777777u) | x2) & 0x88888888u;
        uint32_t prod = ((h1 >> 3) + (h2 >> 3)) * 0x1111u;
        uint32_t xr0 = xr2 & 0xFFFFu, xr1 = xr2 >> 16;
        float rc0 = __builtin_amdgcn_rcpf((float)((prod >> 12) & 15u));
        float rc1 = __builtin_amdgcn_rcpf((float)(prod >> 28));
        float Sv0 = S[g*4 + 2*p], Sv1 = S[g*4 + 2*p + 1];
        float a0 = fmaf(Sv0, 0.12751743f, -0.14426950f);
        float a1 = fmaf(Sv1, 0.12751743f, -0.14426950f);
        a0 = (xr0 == 0u) ? -43.425121f : a0;
        a1 = (xr1 == 0u) ? -43.425121f : a1;
        bool k0 = (xr0 >= 2048u) | (mq16 < (kmp & 0xFFFFu));
        bool k1 = (xr1 >= 2048u) | (mq16 < (kmp >> 16));
        a0 = k0 ? -1e9f : a0;
        a1 = k1 ? -1e9f : a1;
        float e0 = __builtin_amdgcn_exp2f(a0) * rc0;
        float e1 = __builtin_amdgcn_exp2f(a1) * rc1;
        rsp += e0 + e1;
        u[g*2+p] = __builtin_amdgcn_perm(__float_as_uint(e1), __float_as_uint(e0),
                                         0x07060302);   // bf16 pair (lo=e0, hi=e1)
      }
    }
    // ---- build PV B-fragments in registers ----
    asm("v_permlane32_swap_b32 %0, %1" : "+v"(u[0]), "+v"(u[2]));
    asm("v_permlane32_swap_b32 %0, %1" : "+v"(u[1]), "+v"(u[3]));
    asm("v_permlane32_swap_b32 %0, %1" : "+v"(u[4]), "+v"(u[6]));
    asm("v_permlane32_swap_b32 %0, %1" : "+v"(u[5]), "+v"(u[7]));
    union { uint32_t wu[4]; short8 v8; } pf0, pf1;
    pf0.wu[0]=u[0]; pf0.wu[1]=u[1]; pf0.wu[2]=u[2]; pf0.wu[3]=u[3];
    pf1.wu[0]=u[4]; pf1.wu[1]=u[5]; pf1.wu[2]=u[6]; pf1.wu[3]=u[7];
    short8 pb0 = pf0.v8, pb1 = pf1.v8;
    // ---- O^T += V^T * P^T (reads swizzled V^T directly; no mid-barrier) ----
    __builtin_amdgcn_s_setprio(1);
    #pragma unroll
    for (int dt=0; dt<4; dt++){
      int dd = dt*32 + l31;
      int dx = (dd >> 4) & 3;
      short8 va0 = *(const short8*)(Vc + dd*40 + 8*(h ^ dx));
      short8 va1 = *(const short8*)(Vc + dd*40 + 8*((2 + h) ^ dx));
      O[dt] = __builtin_amdgcn_mfma_f32_32x32x16_bf16(va0, pb0, O[dt], 0, 0, 0);
      O[dt] = __builtin_amdgcn_mfma_f32_32x32x16_bf16(va1, pb1, O[dt], 0, 0, 0);
    }
    __builtin_amdgcn_s_setprio(0);
    // ---- write staged slice c+1 into the alternate buffers ----
    if (c < 7){
      uint16_t* kr = Ka + srow*128;
      *(uint4*)(kr + ksw0) = kst0;
      *(uint4*)(kr + ksw1) = kst1;
      uint16_t* vt = Va + (sgp*16)*40 + swz_kv;
      uint32_t vv[8] = {vst0.x,vst0.y,vst0.z,vst0.w,vst1.x,vst1.y,vst1.z,vst1.w};
      #pragma unroll
      for (int i2=0;i2<8;i2++){
        vt[(2*i2)*40]   = (uint16_t)(vv[i2] & 0xFFFFu);
        vt[(2*i2+1)*40] = (uint16_t)(vv[i2] >> 16);
      }
    }
    // swap buffers
    uint16_t* tp;
    tp = Kc; Kc = Ka; Ka = tp;
    tp = Vc; Vc = Va; Va = tp;
  }
  rsp += __shfl_xor(rsp, 32);
  if (lane < 32) rowsum[((gbase + tokq) << 2) + r] = rsp;   // [b][tok][r]
  #pragma unroll
  for (int p=0;p<2;p++){
    __syncthreads();
    if ((w>>1) == p){
      int qloc = (w&1)*32 + l31;
      #pragma unroll
      for (int dt=0; dt<4; dt++)
        #pragma unroll
        for (int g=0; g<4; g++){
          uint2 ow;
          ow.x = pk2(O[dt][g*4+0], O[dt][g*4+1]);
          ow.y = pk2(O[dt][g*4+2], O[dt][g*4+3]);
          *(uint2*)(Qb + qloc*136 + dt*32 + 8*g + 4*h) = ow;
        }
    }
    __syncthreads();
    #pragma unroll
    for (int i=0;i<4;i++){
      int ch = t + i*256;
      int row = ch >> 4, c16 = ch & 15;
      int otok = (int)qtokS[p*64 + row];
      uint4 u2 = *(const uint4*)(Qb + row*136 + c16*8);
      *(uint4*)(attb + (((gbase + otok) << 2) + r)*DK + c16*8) = u2;   // [b][tok][r][d]
    }
  }
}

// ---------------- kernel 4: sum rounds (original order already), normalize ----------------
// attb/rowsum are token-major -> fully coalesced streaming: per token
// 4x256 B contiguous attb + 16 B rowsum; no posA gather at all.
__global__ __launch_bounds__(256) void k_out(const uint16_t* __restrict__ attb,
    const float* __restrict__ rowsum, float* __restrict__ out)
{
  int rloc = threadIdx.x >> 5;                   // 0..7
  int c4   = (threadIdx.x & 31) * 4;             // col base
  int idx  = blockIdx.x*8 + rloc;                // b*LEN + tok
  float n0=0.f, n1=0.f, n2=0.f, n3=0.f, den=0.f;
  #pragma unroll
  for (int r=0;r<4;r++){
    size_t ro = ((size_t)idx << 2) + r;
    uint2 u = *(const uint2*)(attb + ro*DK + c4);
    n0 += bflo(u.x); n1 += bfhi(u.x);
    n2 += bflo(u.y); n3 += bfhi(u.y);
    den += rowsum[ro];
  }
  float rd = 1.0f / den;
  float4 o; o.x = n0*rd; o.y = n1*rd; o.z = n2*rd; o.w = n3*rd;
  *(float4*)(out + (size_t)idx*DK + c4) = o;
}

extern "C" void kernel_launch(void* const* d_in, const int* in_sizes, int n_in,
                              void* d_out, int out_size, void* d_ws, size_t ws_size,
                              hipStream_t stream)
{
  const float* q  = (const float*)d_in[0];
  const float* v  = (const float*)d_in[1];
  const float* rm = (const float*)d_in[3];
  float* out = (float*)d_out;

  char* w = (char*)d_ws;
  uint16_t* fqb    = (uint16_t*)(w + 0);               // 8 MiB normalized q, bf16
  uint16_t* vbb    = (uint16_t*)(w + 8388608);         // 8 MiB value, bf16
  uint8_t*  hsh    = (uint8_t*) (w + 16777216);        // 128 KiB
  int*      posA   = (int*)     (w + 16908288);        // 512 KiB
  int*      tokA   = (int*)     (w + 17432576);        // 512 KiB
  float*    rowsum = (float*)   (w + 18481152);        // 512 KiB [b][tok][r]
  uint16_t* attb   = (uint16_t*)(w + 19005440);        // 32 MiB unnormalized O, bf16 [b][tok][r][d]

  k_hash <<<dim3(BH*32),      dim3(256), 0, stream>>>(q, v, rm, fqb, vbb, hsh);
  k_sort <<<dim3(BH*RND),     dim3(256), 0, stream>>>(hsh, posA, tokA);
  k_fattn<<<dim3(BH*RND*NB2), dim3(256), 0, stream>>>(fqb, vbb, posA, tokA, attb, rowsum);
  k_out  <<<dim3(BH*LEN/8),   dim3(256), 0, stream>>>(attb, rowsum, out);
}

// Round 10
// 152.764 us; speedup vs baseline: 1.2870x; 1.2870x over previous
//
#include <hip/hip_runtime.h>
#include <hip/hip_bf16.h>
#include <stdint.h>

constexpr int BH  = 16;    // batch*head
constexpr int LEN = 2048;
constexpr int DK  = 128;
constexpr int RND = 4;
constexpr int NB2 = 16;    // n_buckets/2 (chunk count)
constexpr int BL2 = 128;   // queries per chunk

typedef __attribute__((ext_vector_type(8)))  short short8;
typedef __attribute__((ext_vector_type(4)))  float f32x4;
typedef __attribute__((ext_vector_type(16))) float f32x16;

__device__ __forceinline__ float bflo(uint32_t u){ return __uint_as_float(u << 16); }
__device__ __forceinline__ float bfhi(uint32_t u){ return __uint_as_float(u & 0xffff0000u); }
__device__ __forceinline__ uint16_t f2b(float x){
  uint32_t u = __float_as_uint(x);
  return (uint16_t)((u + 0x7fffu + ((u >> 16) & 1u)) >> 16);   // RNE
}
__device__ __forceinline__ uint32_t pk2(float a, float b){
  return (uint32_t)f2b(a) | ((uint32_t)f2b(b) << 16);
}

// ---------------- kernel 1: 64 tokens/block; register-tiled fp32 GEMM hash ----------------
// rm_s [d][col] (native layout), qT [d][tok]. Thread (tt,cc) computes 4 tok x 4 col.
// Round r == wave index; argmax combined across col-subgroups via shfl_xor(16/32).
__global__ __launch_bounds__(256) void k_hash(const float* __restrict__ q,
    const float* __restrict__ v, const float* __restrict__ rm,
    uint16_t* __restrict__ fqb, uint16_t* __restrict__ vbb,
    uint8_t* __restrict__ hsh)
{
  __shared__ float rm_s[128*64];    // 32 KB
  __shared__ float qT[128*64];      // 32 KB
  __shared__ float invn_s[64];
  int b = blockIdx.x >> 5, chunk = blockIdx.x & 31;
  int t = threadIdx.x;
  // stage rm straight (it is [d][r][k] row-major = [d][64 cols])
  const float4* rm4 = (const float4*)(rm + (size_t)b*8192);
  #pragma unroll
  for (int i=0;i<8;i++) ((float4*)rm_s)[i*256 + t] = rm4[i*256 + t];
  // stage q (normalize) + bf16 conversions; token tl, d-slice qq*32..+31
  int tl = t >> 2, qq = t & 3;
  int tok = chunk*64 + tl;
  size_t ro = ((size_t)b*LEN + tok)*DK;
  float qs[32];
  float ss = 0.f;
  #pragma unroll
  for (int i=0;i<8;i++){
    float4 w = *(const float4*)(q + ro + qq*32 + i*4);
    qs[i*4]=w.x; qs[i*4+1]=w.y; qs[i*4+2]=w.z; qs[i*4+3]=w.w;
    ss += w.x*w.x + w.y*w.y + w.z*w.z + w.w*w.w;
  }
  ss += __shfl_xor(ss,1); ss += __shfl_xor(ss,2);
  float rn = 1.0f / sqrtf(ss);
  #pragma unroll
  for (int i=0;i<32;i++) qs[i] *= rn;
  #pragma unroll
  for (int i=0;i<4;i++){
    uint4 u;
    u.x = pk2(qs[i*8+0], qs[i*8+1]); u.y = pk2(qs[i*8+2], qs[i*8+3]);
    u.z = pk2(qs[i*8+4], qs[i*8+5]); u.w = pk2(qs[i*8+6], qs[i*8+7]);
    *(uint4*)(fqb + ro + qq*32 + i*8) = u;
  }
  #pragma unroll
  for (int i=0;i<4;i++){
    float4 a = *(const float4*)(v + ro + qq*32 + i*8);
    float4 c = *(const float4*)(v + ro + qq*32 + i*8 + 4);
    uint4 u;
    u.x = pk2(a.x,a.y); u.y = pk2(a.z,a.w); u.z = pk2(c.x,c.y); u.w = pk2(c.z,c.w);
    *(uint4*)(vbb + ro + qq*32 + i*8) = u;
  }
  #pragma unroll
  for (int i=0;i<32;i++) qT[(qq*32+i)*64 + tl] = qs[i];
  __syncthreads();
  if (t < 64){                      // rm column inverse norms (banks spread by t%32)
    float s2 = 0.f;
    for (int d=0; d<128; d++){ float w = rm_s[d*64+t]; s2 += w*w; }
    invn_s[t] = 1.0f / sqrtf(s2);
  }
  // GEMM: 4x4 register tile
  int tt = t & 15, cc = t >> 4;
  f32x4 a0={0,0,0,0}, a1={0,0,0,0}, a2={0,0,0,0}, a3={0,0,0,0};
  const float* qTp = qT   + tt*4;
  const float* rmp = rm_s + cc*4;
  #pragma unroll 8
  for (int d=0; d<128; d++){
    float4 qv = *(const float4*)(qTp + d*64);
    float4 rv = *(const float4*)(rmp + d*64);
    a0[0]+=qv.x*rv.x; a0[1]+=qv.x*rv.y; a0[2]+=qv.x*rv.z; a0[3]+=qv.x*rv.w;
    a1[0]+=qv.y*rv.x; a1[1]+=qv.y*rv.y; a1[2]+=qv.y*rv.z; a1[3]+=qv.y*rv.w;
    a2[0]+=qv.z*rv.x; a2[1]+=qv.z*rv.y; a2[2]+=qv.z*rv.z; a2[3]+=qv.z*rv.w;
    a3[0]+=qv.w*rv.x; a3[1]+=qv.w*rv.y; a3[2]+=qv.w*rv.z; a3[3]+=qv.w*rv.w;
  }
  __syncthreads();                  // invn_s ready
  float rin[4];
  #pragma unroll
  for (int j=0;j<4;j++) rin[j] = invn_s[cc*4+j];
  int r = cc >> 2;                  // round == wave
  int m = cc & 3;                   // col subgroup
  float bp[4], bn[4]; int bip[4], bin[4];
  #pragma unroll
  for (int i=0;i<4;i++){ bp[i]=-1e30f; bn[i]=-1e30f; bip[i]=0; bin[i]=16; }
  #pragma unroll
  for (int j=0;j<4;j++){
    int col = m*4 + j;              // k within round, 0..15
    #pragma unroll
    for (int i=0;i<4;i++){
      float hv = (i==0?a0[j]:i==1?a1[j]:i==2?a2[j]:a3[j]) * rin[j];
      if ( hv > bp[i]){ bp[i] =  hv; bip[i] = col; }
      if (-hv > bn[i]){ bn[i] = -hv; bin[i] = col + 16; }
    }
  }
  #pragma unroll
  for (int off=16; off<=32; off<<=1){
    #pragma unroll
    for (int i=0;i<4;i++){
      float op = __shfl_xor(bp[i], off); int oip = __shfl_xor(bip[i], off);
      if (op > bp[i] || (op == bp[i] && oip < bip[i])){ bp[i]=op; bip[i]=oip; }
      float on = __shfl_xor(bn[i], off); int oin = __shfl_xor(bin[i], off);
      if (on > bn[i] || (on == bn[i] && oin < bin[i])){ bn[i]=on; bin[i]=oin; }
    }
  }
  if (m == 0){                      // one writer per (round, token-group)
    uint32_t pk = 0;
    #pragma unroll
    for (int i=0;i<4;i++){
      int bidx = (bn[i] > bp[i]) ? bin[i] : bip[i];
      pk |= (uint32_t)bidx << (8*i);
    }
    *(uint32_t*)(hsh + ((size_t)(b*RND + r))*LEN + chunk*64 + tt*4) = pk;
  }
}

// ---------------- kernel 2: stable counting sort per (b,r), parallel scan ----------------
// hist padded to stride 257 so the k-major scan reads spread across banks
// (old stride 256: bank == e for all 64 lanes -> 64-way serialization).
__global__ __launch_bounds__(256) void k_sort(const uint8_t* __restrict__ hsh,
    int* __restrict__ posA, int* __restrict__ tokA)
{
  __shared__ int hist[32*257];
  __shared__ int wtot[4];
  int br = blockIdx.x;
  int t = threadIdx.x;
  const uint8_t* hh = hsh + (size_t)br*LEN;
  uint8_t ub[8];
  #pragma unroll
  for (int i=0;i<8;i++) ub[i] = hh[t*8+i];
  #pragma unroll
  for (int k=0;k<32;k++) hist[k*257+t] = 0;
  __syncthreads();
  #pragma unroll
  for (int i=0;i<8;i++) hist[(int)ub[i]*257 + t] += 1;
  __syncthreads();
  // thread t sums bucket k=t>>3, entries t' = (t&7)*32 + e  (k-major flattening)
  int base = (t>>3)*257 + (t&7)*32, s0 = 0;
  for (int e=0;e<32;e++) s0 += hist[base + ((e + t) & 31)];   // rotated: bank-spread
  int x = s0;
  #pragma unroll
  for (int off=1; off<64; off<<=1){
    int y = __shfl_up(x, off);
    if ((t & 63) >= off) x += y;
  }
  if ((t & 63) == 63) wtot[t>>6] = x;
  __syncthreads();
  int add = 0;
  #pragma unroll
  for (int i2=0;i2<4;i2++) add += (i2 < (t>>6)) ? wtot[i2] : 0;
  int run = x - s0 + add;
  for (int e=0;e<32;e++){ int tmp = hist[base+e]; hist[base+e] = run; run += tmp; }
  __syncthreads();
  #pragma unroll
  for (int i=0;i<8;i++){
    int l = t*8+i, k = ub[i];
    int p = hist[k*257+t]++;
    posA[(size_t)br*LEN + l] = p;
    tokA[(size_t)br*LEN + p] = l | (k << 11);
  }
}

// ---------------- kernel 3: fused MFMA attention, 32x32x16 ----------------
// Round 10: EXACT R8 body (48.4 us passing) + s_setprio around MFMA clusters only.
// R9's launch_bounds(256,4) convicted: VGPR 84->64 squeeze -> scratch spills ->
// FETCH 10.5->224 MB, 2x slower. Ks chunk-XOR swizzle also reverted: conflict
// counter proved it a no-op (b128 4-access/bank is the structural floor; row
// stride 256B never enters the bank index) -- pure VALU overhead.
__global__ __launch_bounds__(256, 3) void k_fattn(
    const uint16_t* __restrict__ fqb, const uint16_t* __restrict__ vbb,
    const int* __restrict__ posA, const int* __restrict__ tokA,
    uint16_t* __restrict__ attb, float* __restrict__ rowsum)
{
  __shared__ __align__(16) char smem[40704];
  uint16_t* Ks0 = (uint16_t*)smem;               // 32*136*2 = 8704
  uint16_t* Ks1 = (uint16_t*)(smem + 8704);      // 8704
  uint16_t* VT0 = (uint16_t*)(smem + 17408);     // 128*40*2 = 10240 (swizzled V^T)
  uint16_t* VT1 = (uint16_t*)(smem + 27648);     // 10240
  uint32_t* km4 = (uint32_t*)(smem + 37888);     // 64 groups * 8 words = 2048
  uint16_t* tokS= (uint16_t*)(smem + 39936);     // 256*2 = 512
  uint16_t* qtokS=(uint16_t*)(smem + 40448);     // 128*2 = 256
  uint16_t* Qb  = (uint16_t*)smem;               // epilogue alias (17408 B, Ks dead)

  int bid0 = blockIdx.x;
  int bid = ((bid0 & 7) << 7) | (bid0 >> 3);     // XCD swizzle: each XCD gets 2 b's
  int n = bid & 15, r = (bid>>4)&3, b = bid>>6;
  int t = threadIdx.x;
  int w = t >> 6, lane = t & 63, l31 = lane & 31, h = lane >> 5;
  int br = b*RND + r;
  int sbase = br*LEN, qs0 = n*BL2;
  size_t gbase = (size_t)b*LEN;

  // key metadata (k_meta fused): group gi covers sorted keys 4gi..4gi+3
  // words: [km01, km23, ck01, ck23, cp01, cp23, -, -]
  if (t < 64){
    uint32_t km[4], ck[4], cp[4];
    #pragma unroll
    for (int j=0;j<4;j++){
      int sk4 = t*4 + j;
      int sk = (sk4 < BL2) ? (((n+NB2-1)&15)*BL2 + sk4) : (n*BL2 + sk4 - BL2);
      int raw = tokA[sbase + sk];
      int tok = raw & 2047;
      uint32_t code = 0;
      #pragma unroll
      for (int r2=0;r2<4;r2++){
        int p = posA[(size_t)(b*4+r2)*LEN + tok];
        code |= (uint32_t)(p >> 7) << (4*r2);
      }
      km[j] = (uint32_t)raw & 0xFFFFu;
      ck[j] = code;
      cp[j] = ((code & 0x7777u) + 0x1111u) ^ (code & 0x8888u);
      tokS[sk4] = (uint16_t)tok;
    }
    uint32_t* gp = km4 + t*8;
    gp[0] = km[0] | (km[1]<<16); gp[1] = km[2] | (km[3]<<16);
    gp[2] = ck[0] | (ck[1]<<16); gp[3] = ck[2] | (ck[3]<<16);
    gp[4] = cp[0] | (cp[1]<<16); gp[5] = cp[2] | (cp[3]<<16);
  }
  int raw_q = tokA[sbase + qs0 + w*32 + l31];
  int tokq = raw_q & 2047;
  uint32_t mq16 = (uint32_t)raw_q & 0xFFFFu;
  uint32_t cq = 0;
  #pragma unroll
  for (int r2=0;r2<4;r2++){
    int p = posA[(size_t)(b*4+r2)*LEN + tokq];
    cq |= (uint32_t)(p >> 7) << (4*r2);
  }
  uint32_t mq2 = mq16 | (mq16 << 16);
  uint32_t cq2 = cq | (cq << 16);
  qtokS[w*32 + l31] = (uint16_t)tokq;            // orig token of q-row (dup write by h)
  short8 qf[8];
  {
    const uint16_t* qrow = fqb + (gbase + tokq)*DK + h*8;
    #pragma unroll
    for (int dc=0;dc<8;dc++) qf[dc] = *(const short8*)(qrow + dc*16);
  }

  f32x16 O[4];
  #pragma unroll
  for (int i=0;i<4;i++)
    #pragma unroll
    for (int j=0;j<16;j++) O[i][j] = 0.f;
  float rsp = 0.f;

  int srow = t >> 3, sgp = t & 7;
  // V^T swizzled slot for this thread's kv=srow, d-group sgp (d>>4 == sgp)
  int swz_kv = (srow & 7) + 8*((srow >> 3) ^ (sgp & 3));
  __syncthreads();
  {
    int tok = (int)tokS[srow];
    const uint16_t* fr = fqb + (gbase + tok)*DK;
    const uint16_t* vr = vbb + (gbase + tok)*DK;
    *(uint4*)(Ks0 + srow*136 + sgp*16)     = *(const uint4*)(fr + sgp*16);
    *(uint4*)(Ks0 + srow*136 + sgp*16 + 8) = *(const uint4*)(fr + sgp*16 + 8);
    uint4 v0 = *(const uint4*)(vr + sgp*16);
    uint4 v1 = *(const uint4*)(vr + sgp*16 + 8);
    uint16_t* vt = VT0 + (sgp*16)*40 + swz_kv;
    uint32_t vv[8] = {v0.x,v0.y,v0.z,v0.w,v1.x,v1.y,v1.z,v1.w};
    #pragma unroll
    for (int i2=0;i2<8;i2++){
      vt[(2*i2)*40]   = (uint16_t)(vv[i2] & 0xFFFFu);
      vt[(2*i2+1)*40] = (uint16_t)(vv[i2] >> 16);
    }
  }

  uint16_t* Kc = Ks0; uint16_t* Vc = VT0;
  uint16_t* Ka = Ks1; uint16_t* Va = VT1;

  for (int c=0;c<8;c++){
    __syncthreads();                 // slice-c buffers ready; prior reads done
    // ---- issue stage loads for slice c+1 (latency hides under this whole iter)
    uint4 kst0, kst1, vst0, vst1;
    if (c < 7){
      int tok = (int)tokS[(c+1)*32 + srow];
      const uint16_t* fr = fqb + (gbase + tok)*DK;
      const uint16_t* vr = vbb + (gbase + tok)*DK;
      kst0 = *(const uint4*)(fr + sgp*16);
      kst1 = *(const uint4*)(fr + sgp*16 + 8);
      vst0 = *(const uint4*)(vr + sgp*16);
      vst1 = *(const uint4*)(vr + sgp*16 + 8);
    }
    // ---- S^T = K * Q^T ----
    f32x16 S;
    #pragma unroll
    for (int j=0;j<16;j++) S[j] = 0.f;
    __builtin_amdgcn_s_setprio(1);
    #pragma unroll
    for (int dc=0;dc<8;dc++){
      short8 a = *(const short8*)(Kc + l31*136 + dc*16 + h*8);
      S = __builtin_amdgcn_mfma_f32_32x32x16_bf16(a, qf[dc], S, 0, 0, 0);
    }
    __builtin_amdgcn_s_setprio(0);
    // ---- epilogue: packed 2-keys-per-word mask/count math ----
    uint32_t u[8];
    #pragma unroll
    for (int g=0; g<4; g++){
      const uint32_t* gp = km4 + (c*8 + 2*g + h)*8;
      uint4 A  = *(const uint4*)gp;
      uint2 Bv = *(const uint2*)(gp + 4);
      #pragma unroll
      for (int p=0; p<2; p++){
        uint32_t kmp = p ? A.y : A.x;
        uint32_t ckp = p ? A.w : A.z;
        uint32_t cpp = p ? Bv.y : Bv.x;
        uint32_t xr2 = mq2 ^ kmp;
        uint32_t x1 = cq2 ^ ckp, x2 = cq2 ^ cpp;
        uint32_t h1 = ~(((x1 & 0x77777777u) + 0x77777777u) | x1) & 0x88888888u;
        uint32_t h2 = ~(((x2 & 0x77777777u) + 0x77777777u) | x2) & 0x88888888u;
        uint32_t prod = ((h1 >> 3) + (h2 >> 3)) * 0x1111u;
        uint32_t xr0 = xr2 & 0xFFFFu, xr1 = xr2 >> 16;
        float rc0 = __builtin_amdgcn_rcpf((float)((prod >> 12) & 15u));
        float rc1 = __builtin_amdgcn_rcpf((float)(prod >> 28));
        float Sv0 = S[g*4 + 2*p], Sv1 = S[g*4 + 2*p + 1];
        float a0 = fmaf(Sv0, 0.12751743f, -0.14426950f);
        float a1 = fmaf(Sv1, 0.12751743f, -0.14426950f);
        a0 = (xr0 == 0u) ? -43.425121f : a0;
        a1 = (xr1 == 0u) ? -43.425121f : a1;
        bool k0 = (xr0 >= 2048u) | (mq16 < (kmp & 0xFFFFu));
        bool k1 = (xr1 >= 2048u) | (mq16 < (kmp >> 16));
        a0 = k0 ? -1e9f : a0;
        a1 = k1 ? -1e9f : a1;
        float e0 = __builtin_amdgcn_exp2f(a0) * rc0;
        float e1 = __builtin_amdgcn_exp2f(a1) * rc1;
        rsp += e0 + e1;
        u[g*2+p] = __builtin_amdgcn_perm(__float_as_uint(e1), __float_as_uint(e0),
                                         0x07060302);   // bf16 pair (lo=e0, hi=e1)
      }
    }
    // ---- build PV B-fragments in registers ----
    asm("v_permlane32_swap_b32 %0, %1" : "+v"(u[0]), "+v"(u[2]));
    asm("v_permlane32_swap_b32 %0, %1" : "+v"(u[1]), "+v"(u[3]));
    asm("v_permlane32_swap_b32 %0, %1" : "+v"(u[4]), "+v"(u[6]));
    asm("v_permlane32_swap_b32 %0, %1" : "+v"(u[5]), "+v"(u[7]));
    union { uint32_t wu[4]; short8 v8; } pf0, pf1;
    pf0.wu[0]=u[0]; pf0.wu[1]=u[1]; pf0.wu[2]=u[2]; pf0.wu[3]=u[3];
    pf1.wu[0]=u[4]; pf1.wu[1]=u[5]; pf1.wu[2]=u[6]; pf1.wu[3]=u[7];
    short8 pb0 = pf0.v8, pb1 = pf1.v8;
    // ---- O^T += V^T * P^T (reads swizzled V^T directly; no mid-barrier) ----
    __builtin_amdgcn_s_setprio(1);
    #pragma unroll
    for (int dt=0; dt<4; dt++){
      int dd = dt*32 + l31;
      int dx = (dd >> 4) & 3;
      short8 va0 = *(const short8*)(Vc + dd*40 + 8*(h ^ dx));
      short8 va1 = *(const short8*)(Vc + dd*40 + 8*((2 + h) ^ dx));
      O[dt] = __builtin_amdgcn_mfma_f32_32x32x16_bf16(va0, pb0, O[dt], 0, 0, 0);
      O[dt] = __builtin_amdgcn_mfma_f32_32x32x16_bf16(va1, pb1, O[dt], 0, 0, 0);
    }
    __builtin_amdgcn_s_setprio(0);
    // ---- write staged slice c+1 into the alternate buffers ----
    if (c < 7){
      *(uint4*)(Ka + srow*136 + sgp*16)     = kst0;
      *(uint4*)(Ka + srow*136 + sgp*16 + 8) = kst1;
      uint16_t* vt = Va + (sgp*16)*40 + swz_kv;
      uint32_t vv[8] = {vst0.x,vst0.y,vst0.z,vst0.w,vst1.x,vst1.y,vst1.z,vst1.w};
      #pragma unroll
      for (int i2=0;i2<8;i2++){
        vt[(2*i2)*40]   = (uint16_t)(vv[i2] & 0xFFFFu);
        vt[(2*i2+1)*40] = (uint16_t)(vv[i2] >> 16);
      }
    }
    // swap buffers
    uint16_t* tp;
    tp = Kc; Kc = Ka; Ka = tp;
    tp = Vc; Vc = Va; Va = tp;
  }
  rsp += __shfl_xor(rsp, 32);
  if (lane < 32) rowsum[((gbase + tokq) << 2) + r] = rsp;   // [b][tok][r]
  #pragma unroll
  for (int p=0;p<2;p++){
    __syncthreads();
    if ((w>>1) == p){
      int qloc = (w&1)*32 + l31;
      #pragma unroll
      for (int dt=0; dt<4; dt++)
        #pragma unroll
        for (int g=0; g<4; g++){
          uint2 ow;
          ow.x = pk2(O[dt][g*4+0], O[dt][g*4+1]);
          ow.y = pk2(O[dt][g*4+2], O[dt][g*4+3]);
          *(uint2*)(Qb + qloc*136 + dt*32 + 8*g + 4*h) = ow;
        }
    }
    __syncthreads();
    #pragma unroll
    for (int i=0;i<4;i++){
      int ch = t + i*256;
      int row = ch >> 4, c16 = ch & 15;
      int otok = (int)qtokS[p*64 + row];
      uint4 u2 = *(const uint4*)(Qb + row*136 + c16*8);
      *(uint4*)(attb + (((gbase + otok) << 2) + r)*DK + c16*8) = u2;   // [b][tok][r][d]
    }
  }
}

// ---------------- kernel 4: sum rounds (original order already), normalize ----------------
// attb/rowsum are token-major -> fully coalesced streaming: per token
// 4x256 B contiguous attb + 16 B rowsum; no posA gather at all.
__global__ __launch_bounds__(256) void k_out(const uint16_t* __restrict__ attb,
    const float* __restrict__ rowsum, float* __restrict__ out)
{
  int rloc = threadIdx.x >> 5;                   // 0..7
  int c4   = (threadIdx.x & 31) * 4;             // col base
  int idx  = blockIdx.x*8 + rloc;                // b*LEN + tok
  float n0=0.f, n1=0.f, n2=0.f, n3=0.f, den=0.f;
  #pragma unroll
  for (int r=0;r<4;r++){
    size_t ro = ((size_t)idx << 2) + r;
    uint2 u = *(const uint2*)(attb + ro*DK + c4);
    n0 += bflo(u.x); n1 += bfhi(u.x);
    n2 += bflo(u.y); n3 += bfhi(u.y);
    den += rowsum[ro];
  }
  float rd = 1.0f / den;
  float4 o; o.x = n0*rd; o.y = n1*rd; o.z = n2*rd; o.w = n3*rd;
  *(float4*)(out + (size_t)idx*DK + c4) = o;
}

extern "C" void kernel_launch(void* const* d_in, const int* in_sizes, int n_in,
                              void* d_out, int out_size, void* d_ws, size_t ws_size,
                              hipStream_t stream)
{
  const float* q  = (const float*)d_in[0];
  const float* v  = (const float*)d_in[1];
  const float* rm = (const float*)d_in[3];
  float* out = (float*)d_out;

  char* w = (char*)d_ws;
  uint16_t* fqb    = (uint16_t*)(w + 0);               // 8 MiB normalized q, bf16
  uint16_t* vbb    = (uint16_t*)(w + 8388608);         // 8 MiB value, bf16
  uint8_t*  hsh    = (uint8_t*) (w + 16777216);        // 128 KiB
  int*      posA   = (int*)     (w + 16908288);        // 512 KiB
  int*      tokA   = (int*)     (w + 17432576);        // 512 KiB
  float*    rowsum = (float*)   (w + 18481152);        // 512 KiB [b][tok][r]
  uint16_t* attb   = (uint16_t*)(w + 19005440);        // 32 MiB unnormalized O, bf16 [b][tok][r][d]

  k_hash <<<dim3(BH*32),      dim3(256), 0, stream>>>(q, v, rm, fqb, vbb, hsh);
  k_sort <<<dim3(BH*RND),     dim3(256), 0, stream>>>(hsh, posA, tokA);
  k_fattn<<<dim3(BH*RND*NB2), dim3(256), 0, stream>>>(fqb, vbb, posA, tokA, attb, rowsum);
  k_out  <<<dim3(BH*LEN/8),   dim3(256), 0, stream>>>(attb, rowsum, out);
}

// Round 11
// 150.430 us; speedup vs baseline: 1.3070x; 1.0155x over previous
//
#include <hip/hip_runtime.h>
#include <hip/hip_bf16.h>
#include <stdint.h>

constexpr int BH  = 16;    // batch*head
constexpr int LEN = 2048;
constexpr int DK  = 128;
constexpr int RND = 4;
constexpr int NB2 = 16;    // n_buckets/2 (chunk count)
constexpr int BL2 = 128;   // queries per chunk

typedef __attribute__((ext_vector_type(8)))  short short8;
typedef __attribute__((ext_vector_type(4)))  float f32x4;
typedef __attribute__((ext_vector_type(16))) float f32x16;

__device__ __forceinline__ float bflo(uint32_t u){ return __uint_as_float(u << 16); }
__device__ __forceinline__ float bfhi(uint32_t u){ return __uint_as_float(u & 0xffff0000u); }
__device__ __forceinline__ uint16_t f2b(float x){
  uint32_t u = __float_as_uint(x);
  return (uint16_t)((u + 0x7fffu + ((u >> 16) & 1u)) >> 16);   // RNE
}
__device__ __forceinline__ uint32_t pk2(float a, float b){
  return (uint32_t)f2b(a) | ((uint32_t)f2b(b) << 16);
}

// ---------------- kernel 1: 64 tokens/block; register-tiled fp32 GEMM hash ----------------
// Round 11: qT transpose store de-conflicted via ROTATION swizzle. Old store
// qT[d*64+tl] had bank = tl%32 for all 4 qq-lanes sharing tl (qq*32*64 === 0 mod
// 32 for ANY pad) -> 4-way conflict on 32 scalar stores/thread. New: column
// (tl + 16*qq)&63 -> bank (tl+16*qq)%32 -> 2-way (free). Read side applies the
// same rotation per 32-d block (hoisted: 4 outer blocks, col computed 4x).
__global__ __launch_bounds__(256) void k_hash(const float* __restrict__ q,
    const float* __restrict__ v, const float* __restrict__ rm,
    uint16_t* __restrict__ fqb, uint16_t* __restrict__ vbb,
    uint8_t* __restrict__ hsh)
{
  __shared__ float rm_s[128*64];    // 32 KB
  __shared__ float qT[128*64];      // 32 KB
  __shared__ float invn_s[64];
  int b = blockIdx.x >> 5, chunk = blockIdx.x & 31;
  int t = threadIdx.x;
  // stage rm straight (it is [d][r][k] row-major = [d][64 cols])
  const float4* rm4 = (const float4*)(rm + (size_t)b*8192);
  #pragma unroll
  for (int i=0;i<8;i++) ((float4*)rm_s)[i*256 + t] = rm4[i*256 + t];
  // stage q (normalize) + bf16 conversions; token tl, d-slice qq*32..+31
  int tl = t >> 2, qq = t & 3;
  int tok = chunk*64 + tl;
  size_t ro = ((size_t)b*LEN + tok)*DK;
  float qs[32];
  float ss = 0.f;
  #pragma unroll
  for (int i=0;i<8;i++){
    float4 w = *(const float4*)(q + ro + qq*32 + i*4);
    qs[i*4]=w.x; qs[i*4+1]=w.y; qs[i*4+2]=w.z; qs[i*4+3]=w.w;
    ss += w.x*w.x + w.y*w.y + w.z*w.z + w.w*w.w;
  }
  ss += __shfl_xor(ss,1); ss += __shfl_xor(ss,2);
  float rn = 1.0f / sqrtf(ss);
  #pragma unroll
  for (int i=0;i<32;i++) qs[i] *= rn;
  #pragma unroll
  for (int i=0;i<4;i++){
    uint4 u;
    u.x = pk2(qs[i*8+0], qs[i*8+1]); u.y = pk2(qs[i*8+2], qs[i*8+3]);
    u.z = pk2(qs[i*8+4], qs[i*8+5]); u.w = pk2(qs[i*8+6], qs[i*8+7]);
    *(uint4*)(fqb + ro + qq*32 + i*8) = u;
  }
  #pragma unroll
  for (int i=0;i<4;i++){
    float4 a = *(const float4*)(v + ro + qq*32 + i*8);
    float4 c = *(const float4*)(v + ro + qq*32 + i*8 + 4);
    uint4 u;
    u.x = pk2(a.x,a.y); u.y = pk2(a.z,a.w); u.z = pk2(c.x,c.y); u.w = pk2(c.z,c.w);
    *(uint4*)(vbb + ro + qq*32 + i*8) = u;
  }
  {
    int qcol = (tl + (qq << 4)) & 63;            // rotation swizzle (2-way banks)
    #pragma unroll
    for (int i=0;i<32;i++) qT[(qq*32+i)*64 + qcol] = qs[i];
  }
  __syncthreads();
  if (t < 64){                      // rm column inverse norms (banks spread by t%32)
    float s2 = 0.f;
    for (int d=0; d<128; d++){ float w = rm_s[d*64+t]; s2 += w*w; }
    invn_s[t] = 1.0f / sqrtf(s2);
  }
  // GEMM: 4x4 register tile; qT columns rotated by 16 per 32-d block
  int tt = t & 15, cc = t >> 4;
  f32x4 a0={0,0,0,0}, a1={0,0,0,0}, a2={0,0,0,0}, a3={0,0,0,0};
  const float* rmp = rm_s + cc*4;
  #pragma unroll
  for (int q2=0;q2<4;q2++){
    const float* qTp = qT + (size_t)(q2*32)*64 + (((tt*4) + (q2 << 4)) & 63);
    const float* rmq = rmp + (size_t)(q2*32)*64;
    #pragma unroll 8
    for (int d2=0; d2<32; d2++){
      float4 qv = *(const float4*)(qTp + d2*64);
      float4 rv = *(const float4*)(rmq + d2*64);
      a0[0]+=qv.x*rv.x; a0[1]+=qv.x*rv.y; a0[2]+=qv.x*rv.z; a0[3]+=qv.x*rv.w;
      a1[0]+=qv.y*rv.x; a1[1]+=qv.y*rv.y; a1[2]+=qv.y*rv.z; a1[3]+=qv.y*rv.w;
      a2[0]+=qv.z*rv.x; a2[1]+=qv.z*rv.y; a2[2]+=qv.z*rv.z; a2[3]+=qv.z*rv.w;
      a3[0]+=qv.w*rv.x; a3[1]+=qv.w*rv.y; a3[2]+=qv.w*rv.z; a3[3]+=qv.w*rv.w;
    }
  }
  __syncthreads();                  // invn_s ready
  float rin[4];
  #pragma unroll
  for (int j=0;j<4;j++) rin[j] = invn_s[cc*4+j];
  int r = cc >> 2;                  // round == wave
  int m = cc & 3;                   // col subgroup
  float bp[4], bn[4]; int bip[4], bin[4];
  #pragma unroll
  for (int i=0;i<4;i++){ bp[i]=-1e30f; bn[i]=-1e30f; bip[i]=0; bin[i]=16; }
  #pragma unroll
  for (int j=0;j<4;j++){
    int col = m*4 + j;              // k within round, 0..15
    #pragma unroll
    for (int i=0;i<4;i++){
      float hv = (i==0?a0[j]:i==1?a1[j]:i==2?a2[j]:a3[j]) * rin[j];
      if ( hv > bp[i]){ bp[i] =  hv; bip[i] = col; }
      if (-hv > bn[i]){ bn[i] = -hv; bin[i] = col + 16; }
    }
  }
  #pragma unroll
  for (int off=16; off<=32; off<<=1){
    #pragma unroll
    for (int i=0;i<4;i++){
      float op = __shfl_xor(bp[i], off); int oip = __shfl_xor(bip[i], off);
      if (op > bp[i] || (op == bp[i] && oip < bip[i])){ bp[i]=op; bip[i]=oip; }
      float on = __shfl_xor(bn[i], off); int oin = __shfl_xor(bin[i], off);
      if (on > bn[i] || (on == bn[i] && oin < bin[i])){ bn[i]=on; bin[i]=oin; }
    }
  }
  if (m == 0){                      // one writer per (round, token-group)
    uint32_t pk = 0;
    #pragma unroll
    for (int i=0;i<4;i++){
      int bidx = (bn[i] > bp[i]) ? bin[i] : bip[i];
      pk |= (uint32_t)bidx << (8*i);
    }
    *(uint32_t*)(hsh + ((size_t)(b*RND + r))*LEN + chunk*64 + tt*4) = pk;
  }
}

// ---------------- kernel 2: stable counting sort per (b,r), parallel scan ----------------
// hist padded to stride 257 so the k-major scan reads spread across banks
// (old stride 256: bank == e for all 64 lanes -> 64-way serialization).
__global__ __launch_bounds__(256) void k_sort(const uint8_t* __restrict__ hsh,
    int* __restrict__ posA, int* __restrict__ tokA)
{
  __shared__ int hist[32*257];
  __shared__ int wtot[4];
  int br = blockIdx.x;
  int t = threadIdx.x;
  const uint8_t* hh = hsh + (size_t)br*LEN;
  uint8_t ub[8];
  #pragma unroll
  for (int i=0;i<8;i++) ub[i] = hh[t*8+i];
  #pragma unroll
  for (int k=0;k<32;k++) hist[k*257+t] = 0;
  __syncthreads();
  #pragma unroll
  for (int i=0;i<8;i++) hist[(int)ub[i]*257 + t] += 1;
  __syncthreads();
  // thread t sums bucket k=t>>3, entries t' = (t&7)*32 + e  (k-major flattening)
  int base = (t>>3)*257 + (t&7)*32, s0 = 0;
  for (int e=0;e<32;e++) s0 += hist[base + ((e + t) & 31)];   // rotated: bank-spread
  int x = s0;
  #pragma unroll
  for (int off=1; off<64; off<<=1){
    int y = __shfl_up(x, off);
    if ((t & 63) >= off) x += y;
  }
  if ((t & 63) == 63) wtot[t>>6] = x;
  __syncthreads();
  int add = 0;
  #pragma unroll
  for (int i2=0;i2<4;i2++) add += (i2 < (t>>6)) ? wtot[i2] : 0;
  int run = x - s0 + add;
  for (int e=0;e<32;e++){ int tmp = hist[base+e]; hist[base+e] = run; run += tmp; }
  __syncthreads();
  #pragma unroll
  for (int i=0;i<8;i++){
    int l = t*8+i, k = ub[i];
    int p = hist[k*257+t]++;
    posA[(size_t)br*LEN + l] = p;
    tokA[(size_t)br*LEN + p] = l | (k << 11);
  }
}

// ---------------- kernel 3: fused MFMA attention, 32x32x16 ----------------
// R10 body unchanged (best passing: 47.5 us). Double-buffered Ks/Vs, split
// staging, transposed-V staging (no mid-barrier), k_meta fused, token-major
// outputs, XCD swizzle, packed epilogue, register-P, setprio on MFMA clusters.
__global__ __launch_bounds__(256, 3) void k_fattn(
    const uint16_t* __restrict__ fqb, const uint16_t* __restrict__ vbb,
    const int* __restrict__ posA, const int* __restrict__ tokA,
    uint16_t* __restrict__ attb, float* __restrict__ rowsum)
{
  __shared__ __align__(16) char smem[40704];
  uint16_t* Ks0 = (uint16_t*)smem;               // 32*136*2 = 8704
  uint16_t* Ks1 = (uint16_t*)(smem + 8704);      // 8704
  uint16_t* VT0 = (uint16_t*)(smem + 17408);     // 128*40*2 = 10240 (swizzled V^T)
  uint16_t* VT1 = (uint16_t*)(smem + 27648);     // 10240
  uint32_t* km4 = (uint32_t*)(smem + 37888);     // 64 groups * 8 words = 2048
  uint16_t* tokS= (uint16_t*)(smem + 39936);     // 256*2 = 512
  uint16_t* qtokS=(uint16_t*)(smem + 40448);     // 128*2 = 256
  uint16_t* Qb  = (uint16_t*)smem;               // epilogue alias (17408 B, Ks dead)

  int bid0 = blockIdx.x;
  int bid = ((bid0 & 7) << 7) | (bid0 >> 3);     // XCD swizzle: each XCD gets 2 b's
  int n = bid & 15, r = (bid>>4)&3, b = bid>>6;
  int t = threadIdx.x;
  int w = t >> 6, lane = t & 63, l31 = lane & 31, h = lane >> 5;
  int br = b*RND + r;
  int sbase = br*LEN, qs0 = n*BL2;
  size_t gbase = (size_t)b*LEN;

  // key metadata (k_meta fused): group gi covers sorted keys 4gi..4gi+3
  // words: [km01, km23, ck01, ck23, cp01, cp23, -, -]
  if (t < 64){
    uint32_t km[4], ck[4], cp[4];
    #pragma unroll
    for (int j=0;j<4;j++){
      int sk4 = t*4 + j;
      int sk = (sk4 < BL2) ? (((n+NB2-1)&15)*BL2 + sk4) : (n*BL2 + sk4 - BL2);
      int raw = tokA[sbase + sk];
      int tok = raw & 2047;
      uint32_t code = 0;
      #pragma unroll
      for (int r2=0;r2<4;r2++){
        int p = posA[(size_t)(b*4+r2)*LEN + tok];
        code |= (uint32_t)(p >> 7) << (4*r2);
      }
      km[j] = (uint32_t)raw & 0xFFFFu;
      ck[j] = code;
      cp[j] = ((code & 0x7777u) + 0x1111u) ^ (code & 0x8888u);
      tokS[sk4] = (uint16_t)tok;
    }
    uint32_t* gp = km4 + t*8;
    gp[0] = km[0] | (km[1]<<16); gp[1] = km[2] | (km[3]<<16);
    gp[2] = ck[0] | (ck[1]<<16); gp[3] = ck[2] | (ck[3]<<16);
    gp[4] = cp[0] | (cp[1]<<16); gp[5] = cp[2] | (cp[3]<<16);
  }
  int raw_q = tokA[sbase + qs0 + w*32 + l31];
  int tokq = raw_q & 2047;
  uint32_t mq16 = (uint32_t)raw_q & 0xFFFFu;
  uint32_t cq = 0;
  #pragma unroll
  for (int r2=0;r2<4;r2++){
    int p = posA[(size_t)(b*4+r2)*LEN + tokq];
    cq |= (uint32_t)(p >> 7) << (4*r2);
  }
  uint32_t mq2 = mq16 | (mq16 << 16);
  uint32_t cq2 = cq | (cq << 16);
  qtokS[w*32 + l31] = (uint16_t)tokq;            // orig token of q-row (dup write by h)
  short8 qf[8];
  {
    const uint16_t* qrow = fqb + (gbase + tokq)*DK + h*8;
    #pragma unroll
    for (int dc=0;dc<8;dc++) qf[dc] = *(const short8*)(qrow + dc*16);
  }

  f32x16 O[4];
  #pragma unroll
  for (int i=0;i<4;i++)
    #pragma unroll
    for (int j=0;j<16;j++) O[i][j] = 0.f;
  float rsp = 0.f;

  int srow = t >> 3, sgp = t & 7;
  // V^T swizzled slot for this thread's kv=srow, d-group sgp (d>>4 == sgp)
  int swz_kv = (srow & 7) + 8*((srow >> 3) ^ (sgp & 3));
  __syncthreads();
  {
    int tok = (int)tokS[srow];
    const uint16_t* fr = fqb + (gbase + tok)*DK;
    const uint16_t* vr = vbb + (gbase + tok)*DK;
    *(uint4*)(Ks0 + srow*136 + sgp*16)     = *(const uint4*)(fr + sgp*16);
    *(uint4*)(Ks0 + srow*136 + sgp*16 + 8) = *(const uint4*)(fr + sgp*16 + 8);
    uint4 v0 = *(const uint4*)(vr + sgp*16);
    uint4 v1 = *(const uint4*)(vr + sgp*16 + 8);
    uint16_t* vt = VT0 + (sgp*16)*40 + swz_kv;
    uint32_t vv[8] = {v0.x,v0.y,v0.z,v0.w,v1.x,v1.y,v1.z,v1.w};
    #pragma unroll
    for (int i2=0;i2<8;i2++){
      vt[(2*i2)*40]   = (uint16_t)(vv[i2] & 0xFFFFu);
      vt[(2*i2+1)*40] = (uint16_t)(vv[i2] >> 16);
    }
  }

  uint16_t* Kc = Ks0; uint16_t* Vc = VT0;
  uint16_t* Ka = Ks1; uint16_t* Va = VT1;

  for (int c=0;c<8;c++){
    __syncthreads();                 // slice-c buffers ready; prior reads done
    // ---- issue stage loads for slice c+1 (latency hides under this whole iter)
    uint4 kst0, kst1, vst0, vst1;
    if (c < 7){
      int tok = (int)tokS[(c+1)*32 + srow];
      const uint16_t* fr = fqb + (gbase + tok)*DK;
      const uint16_t* vr = vbb + (gbase + tok)*DK;
      kst0 = *(const uint4*)(fr + sgp*16);
      kst1 = *(const uint4*)(fr + sgp*16 + 8);
      vst0 = *(const uint4*)(vr + sgp*16);
      vst1 = *(const uint4*)(vr + sgp*16 + 8);
    }
    // ---- S^T = K * Q^T ----
    f32x16 S;
    #pragma unroll
    for (int j=0;j<16;j++) S[j] = 0.f;
    __builtin_amdgcn_s_setprio(1);
    #pragma unroll
    for (int dc=0;dc<8;dc++){
      short8 a = *(const short8*)(Kc + l31*136 + dc*16 + h*8);
      S = __builtin_amdgcn_mfma_f32_32x32x16_bf16(a, qf[dc], S, 0, 0, 0);
    }
    __builtin_amdgcn_s_setprio(0);
    // ---- epilogue: packed 2-keys-per-word mask/count math ----
    uint32_t u[8];
    #pragma unroll
    for (int g=0; g<4; g++){
      const uint32_t* gp = km4 + (c*8 + 2*g + h)*8;
      uint4 A  = *(const uint4*)gp;
      uint2 Bv = *(const uint2*)(gp + 4);
      #pragma unroll
      for (int p=0; p<2; p++){
        uint32_t kmp = p ? A.y : A.x;
        uint32_t ckp = p ? A.w : A.z;
        uint32_t cpp = p ? Bv.y : Bv.x;
        uint32_t xr2 = mq2 ^ kmp;
        uint32_t x1 = cq2 ^ ckp, x2 = cq2 ^ cpp;
        uint32_t h1 = ~(((x1 & 0x77777777u) + 0x77777777u) | x1) & 0x88888888u;
        uint32_t h2 = ~(((x2 & 0x77777777u) + 0x77777777u) | x2) & 0x88888888u;
        uint32_t prod = ((h1 >> 3) + (h2 >> 3)) * 0x1111u;
        uint32_t xr0 = xr2 & 0xFFFFu, xr1 = xr2 >> 16;
        float rc0 = __builtin_amdgcn_rcpf((float)((prod >> 12) & 15u));
        float rc1 = __builtin_amdgcn_rcpf((float)(prod >> 28));
        float Sv0 = S[g*4 + 2*p], Sv1 = S[g*4 + 2*p + 1];
        float a0 = fmaf(Sv0, 0.12751743f, -0.14426950f);
        float a1 = fmaf(Sv1, 0.12751743f, -0.14426950f);
        a0 = (xr0 == 0u) ? -43.425121f : a0;
        a1 = (xr1 == 0u) ? -43.425121f : a1;
        bool k0 = (xr0 >= 2048u) | (mq16 < (kmp & 0xFFFFu));
        bool k1 = (xr1 >= 2048u) | (mq16 < (kmp >> 16));
        a0 = k0 ? -1e9f : a0;
        a1 = k1 ? -1e9f : a1;
        float e0 = __builtin_amdgcn_exp2f(a0) * rc0;
        float e1 = __builtin_amdgcn_exp2f(a1) * rc1;
        rsp += e0 + e1;
        u[g*2+p] = __builtin_amdgcn_perm(__float_as_uint(e1), __float_as_uint(e0),
                                         0x07060302);   // bf16 pair (lo=e0, hi=e1)
      }
    }
    // ---- build PV B-fragments in registers ----
    asm("v_permlane32_swap_b32 %0, %1" : "+v"(u[0]), "+v"(u[2]));
    asm("v_permlane32_swap_b32 %0, %1" : "+v"(u[1]), "+v"(u[3]));
    asm("v_permlane32_swap_b32 %0, %1" : "+v"(u[4]), "+v"(u[6]));
    asm("v_permlane32_swap_b32 %0, %1" : "+v"(u[5]), "+v"(u[7]));
    union { uint32_t wu[4]; short8 v8; } pf0, pf1;
    pf0.wu[0]=u[0]; pf0.wu[1]=u[1]; pf0.wu[2]=u[2]; pf0.wu[3]=u[3];
    pf1.wu[0]=u[4]; pf1.wu[1]=u[5]; pf1.wu[2]=u[6]; pf1.wu[3]=u[7];
    short8 pb0 = pf0.v8, pb1 = pf1.v8;
    // ---- O^T += V^T * P^T (reads swizzled V^T directly; no mid-barrier) ----
    __builtin_amdgcn_s_setprio(1);
    #pragma unroll
    for (int dt=0; dt<4; dt++){
      int dd = dt*32 + l31;
      int dx = (dd >> 4) & 3;
      short8 va0 = *(const short8*)(Vc + dd*40 + 8*(h ^ dx));
      short8 va1 = *(const short8*)(Vc + dd*40 + 8*((2 + h) ^ dx));
      O[dt] = __builtin_amdgcn_mfma_f32_32x32x16_bf16(va0, pb0, O[dt], 0, 0, 0);
      O[dt] = __builtin_amdgcn_mfma_f32_32x32x16_bf16(va1, pb1, O[dt], 0, 0, 0);
    }
    __builtin_amdgcn_s_setprio(0);
    // ---- write staged slice c+1 into the alternate buffers ----
    if (c < 7){
      *(uint4*)(Ka + srow*136 + sgp*16)     = kst0;
      *(uint4*)(Ka + srow*136 + sgp*16 + 8) = kst1;
      uint16_t* vt = Va + (sgp*16)*40 + swz_kv;
      uint32_t vv[8] = {vst0.x,vst0.y,vst0.z,vst0.w,vst1.x,vst1.y,vst1.z,vst1.w};
      #pragma unroll
      for (int i2=0;i2<8;i2++){
        vt[(2*i2)*40]   = (uint16_t)(vv[i2] & 0xFFFFu);
        vt[(2*i2+1)*40] = (uint16_t)(vv[i2] >> 16);
      }
    }
    // swap buffers
    uint16_t* tp;
    tp = Kc; Kc = Ka; Ka = tp;
    tp = Vc; Vc = Va; Va = tp;
  }
  rsp += __shfl_xor(rsp, 32);
  if (lane < 32) rowsum[((gbase + tokq) << 2) + r] = rsp;   // [b][tok][r]
  #pragma unroll
  for (int p=0;p<2;p++){
    __syncthreads();
    if ((w>>1) == p){
      int qloc = (w&1)*32 + l31;
      #pragma unroll
      for (int dt=0; dt<4; dt++)
        #pragma unroll
        for (int g=0; g<4; g++){
          uint2 ow;
          ow.x = pk2(O[dt][g*4+0], O[dt][g*4+1]);
          ow.y = pk2(O[dt][g*4+2], O[dt][g*4+3]);
          *(uint2*)(Qb + qloc*136 + dt*32 + 8*g + 4*h) = ow;
        }
    }
    __syncthreads();
    #pragma unroll
    for (int i=0;i<4;i++){
      int ch = t + i*256;
      int row = ch >> 4, c16 = ch & 15;
      int otok = (int)qtokS[p*64 + row];
      uint4 u2 = *(const uint4*)(Qb + row*136 + c16*8);
      *(uint4*)(attb + (((gbase + otok) << 2) + r)*DK + c16*8) = u2;   // [b][tok][r][d]
    }
  }
}

// ---------------- kernel 4: sum rounds (original order already), normalize ----------------
// attb/rowsum are token-major -> fully coalesced streaming: per token
// 4x256 B contiguous attb + 16 B rowsum; no posA gather at all.
__global__ __launch_bounds__(256) void k_out(const uint16_t* __restrict__ attb,
    const float* __restrict__ rowsum, float* __restrict__ out)
{
  int rloc = threadIdx.x >> 5;                   // 0..7
  int c4   = (threadIdx.x & 31) * 4;             // col base
  int idx  = blockIdx.x*8 + rloc;                // b*LEN + tok
  float n0=0.f, n1=0.f, n2=0.f, n3=0.f, den=0.f;
  #pragma unroll
  for (int r=0;r<4;r++){
    size_t ro = ((size_t)idx << 2) + r;
    uint2 u = *(const uint2*)(attb + ro*DK + c4);
    n0 += bflo(u.x); n1 += bfhi(u.x);
    n2 += bflo(u.y); n3 += bfhi(u.y);
    den += rowsum[ro];
  }
  float rd = 1.0f / den;
  float4 o; o.x = n0*rd; o.y = n1*rd; o.z = n2*rd; o.w = n3*rd;
  *(float4*)(out + (size_t)idx*DK + c4) = o;
}

extern "C" void kernel_launch(void* const* d_in, const int* in_sizes, int n_in,
                              void* d_out, int out_size, void* d_ws, size_t ws_size,
                              hipStream_t stream)
{
  const float* q  = (const float*)d_in[0];
  const float* v  = (const float*)d_in[1];
  const float* rm = (const float*)d_in[3];
  float* out = (float*)d_out;

  char* w = (char*)d_ws;
  uint16_t* fqb    = (uint16_t*)(w + 0);               // 8 MiB normalized q, bf16
  uint16_t* vbb    = (uint16_t*)(w + 8388608);         // 8 MiB value, bf16
  uint8_t*  hsh    = (uint8_t*) (w + 16777216);        // 128 KiB
  int*      posA   = (int*)     (w + 16908288);        // 512 KiB
  int*      tokA   = (int*)     (w + 17432576);        // 512 KiB
  float*    rowsum = (float*)   (w + 18481152);        // 512 KiB [b][tok][r]
  uint16_t* attb   = (uint16_t*)(w + 19005440);        // 32 MiB unnormalized O, bf16 [b][tok][r][d]

  k_hash <<<dim3(BH*32),      dim3(256), 0, stream>>>(q, v, rm, fqb, vbb, hsh);
  k_sort <<<dim3(BH*RND),     dim3(256), 0, stream>>>(hsh, posA, tokA);
  k_fattn<<<dim3(BH*RND*NB2), dim3(256), 0, stream>>>(fqb, vbb, posA, tokA, attb, rowsum);
  k_out  <<<dim3(BH*LEN/8),   dim3(256), 0, stream>>>(attb, rowsum, out);
}